// Round 4
// baseline (869.727 us; speedup 1.0000x reference)
//
#include <hip/hip_runtime.h>
#include <hip/hip_bf16.h>

#define N_NODES 200000
#define N_EDGES 3200000
#define FEATS   256
#define NC      32

#define NBPB    512                      // nodes per bucket (dst >> 9)
#define BUCKETS 391                      // ceil(200000 / 512)

typedef __attribute__((ext_vector_type(8))) short bf16x8;
typedef __attribute__((ext_vector_type(4))) float f32x4;

__device__ __forceinline__ float atomAddF(float* p, float v) {
    return unsafeAtomicAdd(p, v);
}
__device__ __forceinline__ short f2bf(float f) {
    return (short)__bfloat16_as_ushort(__float2bfloat16(f));
}

// ---------------------------------------------------------------------------
// Kernel 1: h = x @ W^T + bias via bf16 MFMA. W in registers, x streamed.
// Fused: S1[c] += (u[n]/N)*h[n,c], S2 += (...)^2   (verified round 3)
// ---------------------------------------------------------------------------
__global__ __launch_bounds__(256, 3) void k_linear(
    const float* __restrict__ x, const float* __restrict__ Wmat,
    const float* __restrict__ bias, const float* __restrict__ u_sum,
    float* __restrict__ h, float* __restrict__ S1, float* __restrict__ S2)
{
    __shared__ float lds_s1[4][32];
    __shared__ float lds_s2[4];

    const int lane = threadIdx.x & 63;
    const int wv   = threadIdx.x >> 6;
    const int lr   = lane & 15;
    const int kc   = lane >> 4;

    bf16x8 bfr[8][2];
    #pragma unroll
    for (int ct = 0; ct < 2; ++ct) {
        const float* wp = Wmat + (size_t)(ct * 16 + lr) * FEATS + kc * 8;
        #pragma unroll
        for (int kt = 0; kt < 8; ++kt) {
            f32x4 v0 = *(const f32x4*)(wp + kt * 32);
            f32x4 v1 = *(const f32x4*)(wp + kt * 32 + 4);
            bf16x8 b;
            b[0]=f2bf(v0.x); b[1]=f2bf(v0.y); b[2]=f2bf(v0.z); b[3]=f2bf(v0.w);
            b[4]=f2bf(v1.x); b[5]=f2bf(v1.y); b[6]=f2bf(v1.z); b[7]=f2bf(v1.w);
            bfr[kt][ct] = b;
        }
    }

    const float bias0 = bias[lr], bias1 = bias[16 + lr];
    const float invn = 1.0f / (float)N_NODES;
    float s1_0 = 0.f, s1_1 = 0.f, s2 = 0.f;

    const int ntiles = N_NODES / 16;
    for (int t = blockIdx.x * 4 + wv; t < ntiles; t += gridDim.x * 4) {
        const int base = t * 16;
        const float* xp = x + (size_t)(base + lr) * FEATS + kc * 8;
        f32x4 acc0 = {bias0, bias0, bias0, bias0};
        f32x4 acc1 = {bias1, bias1, bias1, bias1};
        #pragma unroll
        for (int kt = 0; kt < 8; ++kt) {
            f32x4 v0 = *(const f32x4*)(xp + kt * 32);
            f32x4 v1 = *(const f32x4*)(xp + kt * 32 + 4);
            bf16x8 a;
            a[0]=f2bf(v0.x); a[1]=f2bf(v0.y); a[2]=f2bf(v0.z); a[3]=f2bf(v0.w);
            a[4]=f2bf(v1.x); a[5]=f2bf(v1.y); a[6]=f2bf(v1.z); a[7]=f2bf(v1.w);
            acc0 = __builtin_amdgcn_mfma_f32_16x16x32_bf16(a, bfr[kt][0], acc0, 0, 0, 0);
            acc1 = __builtin_amdgcn_mfma_f32_16x16x32_bf16(a, bfr[kt][1], acc1, 0, 0, 0);
        }
        #pragma unroll
        for (int i = 0; i < 4; ++i) {
            const int row = base + kc * 4 + i;
            h[(size_t)row * NC + lr]      = acc0[i];
            h[(size_t)row * NC + 16 + lr] = acc1[i];
            const float um = u_sum[row] * invn;
            float a0 = um * acc0[i], a1 = um * acc1[i];
            s1_0 += a0; s1_1 += a1;
            s2 += a0 * a0 + a1 * a1;
        }
    }

    s1_0 += __shfl_xor(s1_0, 16); s1_0 += __shfl_xor(s1_0, 32);
    s1_1 += __shfl_xor(s1_1, 16); s1_1 += __shfl_xor(s1_1, 32);
    #pragma unroll
    for (int off = 1; off < 64; off <<= 1) s2 += __shfl_xor(s2, off);
    if (lane < 16) { lds_s1[wv][lr] = s1_0; lds_s1[wv][16 + lr] = s1_1; }
    if (lane == 0) lds_s2[wv] = s2;
    __syncthreads();
    if (threadIdx.x < 32) {
        float t4 = lds_s1[0][threadIdx.x] + lds_s1[1][threadIdx.x]
                 + lds_s1[2][threadIdx.x] + lds_s1[3][threadIdx.x];
        atomAddF(&S1[threadIdx.x], t4);
    }
    if (threadIdx.x == 32)
        atomAddF(S2, lds_s2[0] + lds_s2[1] + lds_s2[2] + lds_s2[3]);
}

// ---------------------------------------------------------------------------
// Bucketing: count -> scan -> multisplit scatter (~128B runs per bucket/tile)
// ---------------------------------------------------------------------------
__global__ __launch_bounds__(256) void k_count(
    const int* __restrict__ dst, int* __restrict__ cnt)
{
    __shared__ int hist[BUCKETS];
    for (int i = threadIdx.x; i < BUCKETS; i += 256) hist[i] = 0;
    __syncthreads();
    const int tile = blockIdx.x * 4096;
    #pragma unroll
    for (int i = 0; i < 16; ++i) {
        int e = tile + i * 256 + threadIdx.x;
        if (e < N_EDGES) atomicAdd(&hist[dst[e] >> 9], 1);
    }
    __syncthreads();
    for (int i = threadIdx.x; i < BUCKETS; i += 256)
        if (hist[i]) atomicAdd(&cnt[i], hist[i]);
}

__global__ __launch_bounds__(512) void k_bscan(
    const int* __restrict__ cnt, int* __restrict__ base, int* __restrict__ pos)
{
    __shared__ int sm[512];
    int v = (threadIdx.x < BUCKETS) ? cnt[threadIdx.x] : 0;
    sm[threadIdx.x] = v;
    __syncthreads();
    for (int off = 1; off < 512; off <<= 1) {
        int t = (threadIdx.x >= off) ? sm[threadIdx.x - off] : 0;
        __syncthreads();
        sm[threadIdx.x] += t;
        __syncthreads();
    }
    if (threadIdx.x < BUCKETS) {
        int b = sm[threadIdx.x] - v;
        base[threadIdx.x] = b;
        pos[threadIdx.x]  = b;
    }
}

// payload: x = src | (dst&511)<<18  (src < 2^18), y = w bits
__global__ __launch_bounds__(256) void k_bucket(
    const int* __restrict__ src, const float* __restrict__ w,
    const int* __restrict__ dst, int* __restrict__ pos,
    int2* __restrict__ bucketed)
{
    __shared__ int hist[BUCKETS];
    __shared__ int cursor[BUCKETS];
    for (int i = threadIdx.x; i < BUCKETS; i += 256) hist[i] = 0;
    __syncthreads();

    const int tile = blockIdx.x * 4096;
    int bb[16], dd[16];
    #pragma unroll
    for (int i = 0; i < 16; ++i) {
        int e = tile + i * 256 + threadIdx.x;
        if (e < N_EDGES) {
            dd[i] = dst[e];
            bb[i] = dd[i] >> 9;
            atomicAdd(&hist[bb[i]], 1);
        } else bb[i] = -1;
    }
    __syncthreads();
    for (int i = threadIdx.x; i < BUCKETS; i += 256) {
        int hc = hist[i];
        cursor[i] = hc ? atomicAdd(&pos[i], hc) : 0;
    }
    __syncthreads();
    #pragma unroll
    for (int i = 0; i < 16; ++i) {
        if (bb[i] >= 0) {
            int e = tile + i * 256 + threadIdx.x;
            int p = atomicAdd(&cursor[bb[i]], 1);
            int2 v;
            v.x = src[e] | ((dd[i] & (NBPB - 1)) << 18);
            v.y = __float_as_int(w[e]);
            bucketed[p] = v;
        }
    }
}

// ---------------------------------------------------------------------------
// Per-bucket reduce: y-chunk (64 KB) in LDS, ds_add_f32 accumulate,
// single coalesced write-out, colsum fused.
// ---------------------------------------------------------------------------
__global__ __launch_bounds__(512, 2) void k_breduce(
    const int2* __restrict__ bucketed, const int* __restrict__ base,
    const int* __restrict__ cnt, const float* __restrict__ h,
    float* __restrict__ y, float* __restrict__ colsum)
{
    __shared__ float ych[NBPB * NC];     // 64 KB
    __shared__ float red[512];
    const int c = threadIdx.x & 31;
    const int g = threadIdx.x >> 5;      // 0..15
    float scol = 0.f;

    for (int b = blockIdx.x; b < BUCKETS; b += gridDim.x) {
        for (int i = threadIdx.x; i < NBPB * NC; i += 512) ych[i] = 0.f;
        __syncthreads();

        const int beg = base[b], n = cnt[b];
        // 2-wide software pipeline: both h-gathers in flight before atomics
        int j = g;
        for (; j + 16 < n; j += 32) {
            int2 p0 = bucketed[beg + j];
            int2 p1 = bucketed[beg + j + 16];
            float v0 = h[(size_t)(p0.x & 0x3FFFF) * NC + c] * __int_as_float(p0.y);
            float v1 = h[(size_t)(p1.x & 0x3FFFF) * NC + c] * __int_as_float(p1.y);
            atomicAdd(&ych[((unsigned)p0.x >> 18) * NC + c], v0);
            atomicAdd(&ych[((unsigned)p1.x >> 18) * NC + c], v1);
        }
        if (j < n) {
            int2 p0 = bucketed[beg + j];
            float v0 = h[(size_t)(p0.x & 0x3FFFF) * NC + c] * __int_as_float(p0.y);
            atomicAdd(&ych[((unsigned)p0.x >> 18) * NC + c], v0);
        }
        __syncthreads();

        const int node0 = b * NBPB;
        const int nelem = (N_NODES - node0 < NBPB ? N_NODES - node0 : NBPB) * NC;
        for (int i = threadIdx.x; i < nelem; i += 512) {  // i&31 const per thread
            float v = ych[i];
            y[(size_t)node0 * NC + i] = v;
            scol += v;
        }
        __syncthreads();
    }

    red[threadIdx.x] = scol;
    __syncthreads();
    if (threadIdx.x < 32) {
        float t = 0.f;
        #pragma unroll
        for (int jj = 0; jj < 16; ++jj) t += red[threadIdx.x + 32 * jj];
        atomAddF(&colsum[threadIdx.x], t);
    }
}

// ---------------------------------------------------------------------------
// Fallback path (small workspace)
// ---------------------------------------------------------------------------
__global__ __launch_bounds__(256) void k_scatter_atomic(
    const float* __restrict__ h, const float* __restrict__ w,
    const int* __restrict__ src, const int* __restrict__ dst,
    float* __restrict__ y)
{
    const long long total  = (long long)N_EDGES * NC;
    const long long stride = (long long)gridDim.x * 256;
    for (long long i = (long long)blockIdx.x * 256 + threadIdx.x;
         i < total; i += stride) {
        const int e = (int)(i >> 5);
        const int c = (int)(i & 31);
        atomAddF(&y[(size_t)dst[e] * NC + c], h[(size_t)src[e] * NC + c] * w[e]);
    }
}

__global__ __launch_bounds__(256) void k_colsum(
    const float* __restrict__ y, float* __restrict__ colsum)
{
    __shared__ float red[256];
    const long long total  = (long long)N_NODES * NC;
    const long long stride = (long long)gridDim.x * 256;
    float s = 0.f;
    for (long long i = (long long)blockIdx.x * 256 + threadIdx.x;
         i < total; i += stride)
        s += y[i];
    red[threadIdx.x] = s;
    __syncthreads();
    if (threadIdx.x < 32) {
        float t = 0.f;
        #pragma unroll
        for (int j = 0; j < 8; ++j) t += red[threadIdx.x + 32 * j];
        atomAddF(&colsum[threadIdx.x], t);
    }
}

// ---------------------------------------------------------------------------
// loss; acc: [0..31] colsum_y, [32..63] S1, [64] S2
// ---------------------------------------------------------------------------
__global__ void k_final(const float* __restrict__ acc, float* __restrict__ loss_out)
{
    double cross = 0.0, msq = 0.0;
    for (int c = 0; c < NC; ++c) {
        double m = (double)acc[c] / (double)N_NODES;
        cross += m * (double)acc[32 + c];
        msq   += m * m;
    }
    double loss = ((double)acc[64] - 2.0 * cross + (double)N_NODES * msq)
                  / ((double)N_NODES * (double)NC);
    *loss_out = (float)loss;
}

extern "C" void kernel_launch(void* const* d_in, const int* in_sizes, int n_in,
                              void* d_out, int out_size, void* d_ws, size_t ws_size,
                              hipStream_t stream)
{
    const float* x   = (const float*)d_in[0];
    const float* w   = (const float*)d_in[1];
    const float* u   = (const float*)d_in[2];
    const float* Wm  = (const float*)d_in[3];
    const float* Wb  = (const float*)d_in[4];
    const int*   src = (const int*)d_in[5];
    const int*   dst = (const int*)d_in[6];

    float* out = (float*)d_out;                  // y [N*32] then loss [1]

    uint8_t* w8 = (uint8_t*)d_ws;
    float* acc  = (float*)w8;                    // 256 floats
    int*   cnt  = (int*)(w8 + 1024);             // BUCKETS (padded 512)
    int*   base = cnt + 512;
    int*   pos  = base + 512;
    float* h    = (float*)(pos + 512);           // 25.6 MB
    int2*  bucketed = (int2*)(h + (size_t)N_NODES * NC);  // 25.6 MB

    const size_t need = 1024 + 3 * 512 * 4
                      + (size_t)N_NODES * NC * 4 + (size_t)N_EDGES * 8;

    hipMemsetAsync(acc, 0, 256 * sizeof(float), stream);

    const int NBK = (N_EDGES + 4095) / 4096;     // 782

    if (ws_size >= need) {
        hipMemsetAsync(cnt, 0, BUCKETS * sizeof(int), stream);

        k_linear <<<1024, 256, 0, stream>>>(x, Wm, Wb, u, h, acc + 32, acc + 64);
        k_count  <<<NBK, 256, 0, stream>>>(dst, cnt);
        k_bscan  <<<1, 512, 0, stream>>>(cnt, base, pos);
        k_bucket <<<NBK, 256, 0, stream>>>(src, w, dst, pos, bucketed);
        k_breduce<<<BUCKETS, 512, 0, stream>>>(bucketed, base, cnt, h, out, acc);
    } else {
        float* h2 = (float*)w8 + 256;
        hipMemsetAsync(d_out, 0, (size_t)out_size * sizeof(float), stream);
        k_linear        <<<1024, 256, 0, stream>>>(x, Wm, Wb, u, h2, acc + 32, acc + 64);
        k_scatter_atomic<<<8192, 256, 0, stream>>>(h2, w, src, dst, out);
        k_colsum        <<<2048, 256, 0, stream>>>(out, acc);
    }

    k_final<<<1, 1, 0, stream>>>(acc, out + (size_t)N_NODES * NC);
}